// Round 10
// baseline (564.454 us; speedup 1.0000x reference)
//
#include <hip/hip_runtime.h>
#include <hip/hip_bf16.h>

// CapsNet forward. Round 21: k_mmat_aij route-batching. Old: 1152 blocks, each
// reading 16B of u_bf per batch-row (quarter of a 64B line -> line fetched by
// up to 4 blocks; FETCH 27.4MB vs 10.6MB logical). New: 4 routes per block
// (288 blocks), one aligned 64B u_bf load per row -> u traffic = logical size;
// v re-reads drop 4x. Per-route arithmetic order IDENTICAL (same b-partition,
// same reduction tree) -> bit-exact; absmax must stay exactly 0.0003356934.
// XCD ownership kept: r0 = ((bid&7)*36+(bid>>3))*4. All else byte-identical
// to round 20. B=256, R=1152, C=10, O=16, I=8

typedef __bf16 bf16x8 __attribute__((ext_vector_type(8)));
typedef float  f32x4  __attribute__((ext_vector_type(4)));
typedef ushort u16x8  __attribute__((ext_vector_type(8)));

static __device__ __forceinline__ ushort f2bf(float f) {
    __hip_bfloat16 h = __float2bfloat16(f);
    return *(ushort*)&h;
}
static __device__ __forceinline__ float b2f(ushort u) {
    return __uint_as_float(((unsigned)u) << 16);
}

// direct global->LDS DMA, 16B per lane; LDS dest = wave-uniform base + lane*16
typedef __attribute__((address_space(1))) const unsigned int* as1_u32p;
typedef __attribute__((address_space(3))) unsigned int* as3_u32p;
static __device__ __forceinline__ void gl16(const void* g, void* l) {
    __builtin_amdgcn_global_load_lds((as1_u32p)g, (as3_u32p)l, 16, 0, 0);
}

// ---------------- fused prep: Awt (256) | Wt (144) | small (296) ----------------
__global__ __launch_bounds__(256) void k_prep_fused(
    const float* __restrict__ w1, const float* __restrict__ w2,
    const float* __restrict__ pw, const float* __restrict__ W,
    __hip_bfloat16* __restrict__ Aw1, __hip_bfloat16* __restrict__ Aw2,
    __hip_bfloat16* __restrict__ Awt, __hip_bfloat16* __restrict__ Wt)
{
    __shared__ float ls[10368];               // 41.5 KB (max of both transposes)
    const int bid = blockIdx.x;
    const int tid = threadIdx.x;
    if (bid < 256) {
        // Awt[oc][k81][ic] = pw[oc][ic][k81]; stride-81 LDS read: conflict-free
        const int oc = bid;
        const float* src = pw + oc * 10368;
        for (int i = tid; i < 10368; i += 256) ls[i] = src[i];
        __syncthreads();
        __hip_bfloat16* dst = Awt + oc * 10368;
        for (int o = tid; o < 10368; o += 256) {
            int k81 = o >> 7, ic = o & 127;
            dst[o] = __float2bfloat16(ls[ic * 81 + k81]);
        }
    } else if (bid < 400) {
        // Wt[co][r*8+i] = W[r][c][o][i]; 8 rows of 1280 padded to 1281
        const int r0 = (bid - 256) * 8;
        const float* src = W + (size_t)r0 * 1280;
        for (int i = tid; i < 10240; i += 256) {
            int rr = i / 1280, rem = i - rr * 1280;
            ls[rr * 1281 + rem] = src[i];
        }
        __syncthreads();
        for (int o = tid; o < 10240; o += 256) {
            int co = o >> 6, rem = o & 63;
            int rr = rem >> 3, i = rem & 7;
            Wt[(size_t)co * 9216 + r0 * 8 + rem] =
                __float2bfloat16(ls[rr * 1281 + co * 8 + i]);
        }
    } else {
        int t = (bid - 400) * 256 + tid;      // 75,776 threads
        if (t < 73728) {
            int oc = t / 576, rem = t % 576;
            int k9 = rem >> 6, ic = rem & 63;
            Aw2[t] = __float2bfloat16(w2[(oc * 64 + ic) * 9 + k9]);
        } else if (t < 75776) {
            int q = t - 73728;
            int oc = q >> 5, k = q & 31;
            Aw1[q] = __float2bfloat16(k < 27 ? w1[oc * 27 + k] : 0.f);
        }
    }
}

// ---------------- conv1(3->64,3x3,s1,p0) + relu + maxpool(2,2,p1) via MFMA -------
__global__ __launch_bounds__(256) void k_conv1_mfma(
    const float* __restrict__ data, const __hip_bfloat16* __restrict__ Aw1,
    const float* __restrict__ b1, __hip_bfloat16* __restrict__ P1t)
{
    __shared__ float tile[960];          // [ic]*312 + [rloc]*78 + [lc]; lc = x_in+1
    const int tid = threadIdx.x;
    const int py = blockIdx.x % 38, b = blockIdx.x / 38;

    #pragma unroll
    for (int c = 0; c < 4; c++) {
        int idx = tid + c * 256;
        if (idx < 960) {
            float val = 0.f;
            if (idx < 936) {
                int ic = idx / 312, rem = idx % 312;
                int rl = rem / 78, lc = rem % 78;
                int ri = 2 * py - 1 + rl, xi = lc - 1;
                if ((unsigned)ri < 76u && (unsigned)xi < 76u)
                    val = data[(b * 3 + ic) * 5776 + ri * 76 + xi];
            }
            tile[idx] = val;
        }
    }

    const int wave = tid >> 6, lane = tid & 63;
    const int l15 = lane & 15, quad = lane >> 4;

    bf16x8 af = *(const bf16x8*)((const ushort*)Aw1 + (wave * 16 + l15) * 32 + quad * 8);

    int koff[8]; bool kok[8];
    #pragma unroll
    for (int j = 0; j < 8; j++) {
        int kk = quad * 8 + j;
        kok[j] = kk < 27;
        int ic = kk / 9, rem = kk - ic * 9, ky = rem / 3, kx = rem - ky * 3;
        koff[j] = kok[j] ? (ic * 312 + ky * 78 + kx) : 0;
    }

    float bias[4];
    #pragma unroll
    for (int r = 0; r < 4; r++) bias[r] = b1[wave * 16 + quad * 4 + r];

    const bool valid0 = (py > 0);
    const bool valid1 = (py < 37);

    __syncthreads();

    #pragma unroll
    for (int t5 = 0; t5 < 5; t5++) {
        int n_x = t5 * 16 + l15;                         // conv x = n_x - 1
        bool col_ok = (unsigned)(n_x - 1) < 74u;

        bf16x8 bf0, bf1;
        #pragma unroll
        for (int j = 0; j < 8; j++) {
            float v0 = tile[koff[j] + n_x];
            float v1 = tile[koff[j] + 78 + n_x];
            bool ok = col_ok && kok[j];
            bf0[j] = (__bf16)(ok ? v0 : 0.f);
            bf1[j] = (__bf16)(ok ? v1 : 0.f);
        }
        f32x4 z = {0.f, 0.f, 0.f, 0.f};
        f32x4 c0 = __builtin_amdgcn_mfma_f32_16x16x32_bf16(af, bf0, z, 0, 0, 0);
        f32x4 c1 = __builtin_amdgcn_mfma_f32_16x16x32_bf16(af, bf1, z, 0, 0, 0);

        f32x4 p;
        #pragma unroll
        for (int r = 0; r < 4; r++) {
            float r0 = (valid0 && col_ok) ? fmaxf(c0[r] + bias[r], 0.f) : 0.f;
            float r1 = (valid1 && col_ok) ? fmaxf(c1[r] + bias[r], 0.f) : 0.f;
            p[r] = fmaxf(r0, r1);
        }
        #pragma unroll
        for (int r = 0; r < 4; r++)
            p[r] = fmaxf(p[r], __shfl_xor(p[r], 1));

        if (!(l15 & 1)) {
            int px = t5 * 8 + (l15 >> 1);
            if (px < 38) {
                ushort4 pk;
                pk.x = f2bf(p[0]); pk.y = f2bf(p[1]);
                pk.z = f2bf(p[2]); pk.w = f2bf(p[3]);
                *(ushort4*)((ushort*)P1t + ((size_t)(b * 38 + py) * 38 + px) * 64
                            + wave * 16 + quad * 4) = pk;
            }
        }
    }
}

// ---------------- conv2 MFMA + bias + relu + FUSED maxpool(2,2,p1) --------------
// (256,4): known-good VGPR=64 operating point; stride-136 epilogue gather.
__global__ __launch_bounds__(256, 4) void k_conv2_pool_mfma(
    const __hip_bfloat16* __restrict__ P1t,   // [256][38][38][64]
    const __hip_bfloat16* __restrict__ Aw2,   // [128][576]
    const float* __restrict__ cb,             // [128]
    const ushort* __restrict__ zpage,         // 128 B of zeros
    __hip_bfloat16* __restrict__ P2t)         // [256][20][20][128]
{
    __shared__ ushort lA[128 * 64];           // 16,384 B linear
    __shared__ ushort lB[128 * 64];           // 16,384 B linear
    const int tid  = threadIdx.x;
    const int grp  = blockIdx.x / 50, toff = blockIdx.x % 50;
    const int wave = tid >> 6, lane = tid & 63;
    const int wm   = wave & 1, wn = wave >> 1;      // 2 x 2 waves
    const int lane15 = lane & 15, quad = lane >> 4;

    const int sl = ((lane & 7) ^ (lane >> 3)) * 8;   // pre-swizzled source slot

    int oA[4], oB[4], yv[4], xv[4];
    #pragma unroll
    for (int i = 0; i < 4; i++) {
        int row = wave * 32 + i * 8 + (lane >> 3);
        oA[i] = row * 576 + sl;
        int off = toff * 128 + row;                  // 0..6399 within group
        int bb = off / 1600, rem = off % 1600;
        int cell = rem >> 2, q = rem & 3;
        int py = cell / 20, px = cell % 20;
        int y = 2 * py - 1 + (q >> 1), x = 2 * px - 1 + (q & 1);
        yv[i] = y; xv[i] = x;
        oB[i] = (((grp * 4 + bb) * 38 + (y - 1)) * 38 + (x - 1)) * 64 + sl;
    }
    ushort* lAq = &lA[wave * 2048];
    ushort* lBq = &lB[wave * 2048];

    const int s7 = lane15 & 7;
    const int c0 = (quad ^ s7) * 8;                  // kk=0 slot (ushorts)
    const int c1 = ((quad + 4) ^ s7) * 8;            // kk=1 slot
    const ushort* aRd0 = &lA[(wm * 64 + lane15) * 64 + c0];
    const ushort* aRd1 = &lA[(wm * 64 + lane15) * 64 + c1];
    const ushort* bRd0 = &lB[(wn * 64 + lane15) * 64 + c0];
    const ushort* bRd1 = &lB[(wn * 64 + lane15) * 64 + c1];

    f32x4 zero = {0.f, 0.f, 0.f, 0.f};
    f32x4 acc[4][4];
    #pragma unroll
    for (int i = 0; i < 4; i++)
        #pragma unroll
        for (int j = 0; j < 4; j++) acc[i][j] = zero;

    for (int kb = 0; kb < 9; kb++) {                      // tap (ky,kx), 64 ic each
        int ky = kb / 3, kx = kb - ky * 3;
        int dB = (ky * 38 + kx) << 6;
        int dA = kb << 6;

        __syncthreads();                                  // prev reads done
        #pragma unroll
        for (int i = 0; i < 4; i++) {
            gl16((const ushort*)Aw2 + oA[i] + dA, lAq + i * 512);
            bool ok = ((unsigned)(yv[i] - 1 + ky) < 38u) &&
                      ((unsigned)(xv[i] - 1 + kx) < 38u);
            const ushort* src = ok ? ((const ushort*)P1t + (ptrdiff_t)(oB[i] + dB))
                                   : (zpage + sl);
            gl16(src, lBq + i * 512);
        }
        __syncthreads();                                  // DMA drained

        #pragma unroll
        for (int kk = 0; kk < 2; kk++) {
            const ushort* ap = kk ? aRd1 : aRd0;
            const ushort* bp = kk ? bRd1 : bRd0;
            bf16x8 af[4], bf[4];
            #pragma unroll
            for (int tm = 0; tm < 4; tm++)
                af[tm] = *(const bf16x8*)(ap + tm * 1024);
            #pragma unroll
            for (int tn = 0; tn < 4; tn++)
                bf[tn] = *(const bf16x8*)(bp + tn * 1024);
            #pragma unroll
            for (int tm = 0; tm < 4; tm++)
                #pragma unroll
                for (int tn = 0; tn < 4; tn++)
                    acc[tm][tn] = __builtin_amdgcn_mfma_f32_16x16x32_bf16(
                        af[tm], bf[tn], acc[tm][tn], 0, 0, 0);
        }
    }

    // epilogue: relu(val+bias), zero invalid quadrants, pool via shfl,
    // gather eq==0 results in LDS [32 cells][136 stride], coalesced burst out.
    __syncthreads();                          // all MFMA-phase LDS reads done
    ushort* lout = lA;                        // reuse (32*136 ushorts = 8.5KB)
    #pragma unroll
    for (int tn = 0; tn < 4; tn++) {
        int woff = toff * 128 + wn * 64 + tn * 16 + lane15;
        int ebb = woff / 1600, erem = woff % 1600;
        int ecell = erem >> 2, eq = erem & 3;
        int epy = ecell / 20, epx = ecell % 20;
        int ey = 2 * epy - 1 + (eq >> 1), ex = 2 * epx - 1 + (eq & 1);
        bool vq = ((unsigned)ey < 38u) && ((unsigned)ex < 38u);
        int c32 = wn * 16 + tn * 4 + (lane15 >> 2);      // block-local cell
        #pragma unroll
        for (int tm = 0; tm < 4; tm++) {
            int m0 = wm * 64 + tm * 16 + quad * 4;
            f32x4 a = acc[tm][tn];
            f32x4 p;
            #pragma unroll
            for (int r = 0; r < 4; r++)
                p[r] = vq ? fmaxf(a[r] + cb[m0 + r], 0.f) : 0.f;
            #pragma unroll
            for (int r = 0; r < 4; r++) {
                p[r] = fmaxf(p[r], __shfl_xor(p[r], 1));
                p[r] = fmaxf(p[r], __shfl_xor(p[r], 2));
            }
            if (eq == 0) {
                ushort4 pk;
                pk.x = f2bf(p[0]); pk.y = f2bf(p[1]);
                pk.z = f2bf(p[2]); pk.w = f2bf(p[3]);
                *(ushort4*)(lout + c32 * 136 + m0) = pk;
            }
        }
    }
    __syncthreads();
    {
        int c32 = tid >> 3, part = tid & 7;              // 8 threads x 32B per cell
        int woff = toff * 128 + c32 * 4;                 // the q==0 row of the cell
        int ebb = woff / 1600, erem = woff % 1600;
        int ecell = erem >> 2;
        int epy = ecell / 20, epx = ecell % 20;
        int eb = grp * 4 + ebb;
        const uint4* src = (const uint4*)(lout + c32 * 136 + part * 16);
        uint4* dst = (uint4*)((ushort*)P2t
                     + (((size_t)eb * 20 + epy) * 20 + epx) * 128 + part * 16);
        dst[0] = src[0];
        dst[1] = src[1];
    }
}

// ---------------- primcaps split-K MFMA GEMM, 128x128 tile, gl16 staging --------
__global__ __launch_bounds__(256, 4) void k_primcaps_mfma(
    const __hip_bfloat16* __restrict__ P2t,   // [256][20][20][128]
    const __hip_bfloat16* __restrict__ Awt,   // [256][10368]
    float* __restrict__ partU)                // [6][256][9216]
{
    __shared__ ushort lA[128 * 64];           // 16,384 B linear
    __shared__ ushort lB[128 * 64];           // 16,384 B linear
    const int tid  = threadIdx.x;
    const int chunk = blockIdx.x / 144;
    const int tile  = blockIdx.x % 144;
    const int bm   = tile & 1;
    const int bn   = tile >> 1;               // 0..71
    const int wave = tid >> 6, lane = tid & 63;
    const int wm   = wave & 1, wn = wave >> 1;
    const int lane15 = lane & 15, quad = lane >> 4;

    const int sl = ((lane & 7) ^ (lane >> 3)) * 8;

    int oA[4], oB[4];
    #pragma unroll
    for (int i = 0; i < 4; i++) {
        int row = wave * 32 + i * 8 + (lane >> 3);
        oA[i] = (bm * 128 + row) * 10368 + sl;
        int n = bn * 128 + row;
        int cbn = n / 36, cs = n % 36;
        int cy = cs / 6, cx = cs % 6;
        oB[i] = ((cbn * 20 + 2 * cy) * 20 + 2 * cx) * 128 + sl;
    }
    ushort* lAq = &lA[wave * 2048];
    ushort* lBq = &lB[wave * 2048];

    const int s7 = lane15 & 7;
    const int c0 = (quad ^ s7) * 8;
    const int c1 = ((quad + 4) ^ s7) * 8;
    const ushort* aRd0 = &lA[(wm * 64 + lane15) * 64 + c0];
    const ushort* aRd1 = &lA[(wm * 64 + lane15) * 64 + c1];
    const ushort* bRd0 = &lB[(wn * 64 + lane15) * 64 + c0];
    const ushort* bRd1 = &lB[(wn * 64 + lane15) * 64 + c1];

    f32x4 zero = {0.f, 0.f, 0.f, 0.f};
    f32x4 acc[4][4];
    #pragma unroll
    for (int i = 0; i < 4; i++)
        #pragma unroll
        for (int j = 0; j < 4; j++) acc[i][j] = zero;

    const int kb0 = chunk * 27;
    for (int ki = 0; ki < 27; ki++) {
        int kb = kb0 + ki;
        int k81 = kb >> 1;
        int ky = k81 / 9, kx = k81 - ky * 9;
        int dB = (ky * 20 + kx) * 128 + (kb & 1) * 64;
        int dA = kb << 6;

        __syncthreads();
        #pragma unroll
        for (int i = 0; i < 4; i++) {
            gl16((const ushort*)Awt + (size_t)oA[i] + dA, lAq + i * 512);
            gl16((const ushort*)P2t + oB[i] + dB, lBq + i * 512);
        }
        __syncthreads();

        #pragma unroll
        for (int kk = 0; kk < 2; kk++) {
            const ushort* ap = kk ? aRd1 : aRd0;
            const ushort* bp = kk ? bRd1 : bRd0;
            bf16x8 af[4], bf[4];
            #pragma unroll
            for (int tm = 0; tm < 4; tm++)
                af[tm] = *(const bf16x8*)(ap + tm * 1024);
            #pragma unroll
            for (int tn = 0; tn < 4; tn++)
                bf[tn] = *(const bf16x8*)(bp + tn * 1024);
            #pragma unroll
            for (int tm = 0; tm < 4; tm++)
                #pragma unroll
                for (int tn = 0; tn < 4; tn++)
                    acc[tm][tn] = __builtin_amdgcn_mfma_f32_16x16x32_bf16(
                        af[tm], bf[tn], acc[tm][tn], 0, 0, 0);
        }
    }

    float* base = partU + (size_t)chunk * 2359296;
    #pragma unroll
    for (int tm = 0; tm < 4; tm++) {
        int m0 = bm * 128 + wm * 64 + tm * 16 + quad * 4;
        #pragma unroll
        for (int tn = 0; tn < 4; tn++) {
            int nn = bn * 128 + wn * 64 + tn * 16 + lane15;
            f32x4 a = acc[tm][tn];
            #pragma unroll
            for (int r = 0; r < 4; r++)
                base[(size_t)(m0 + r) * 9216 + nn] = a[r];   // lane-consecutive
        }
    }
}

// ---------------- reduce 6 partials + bias + squash -> u_bf [b][k] bf16 ----------
// partU layout [chunk][m(256)][n=b*36+os]; thread t covers b=t/1152,
// flat f = (t%1152)*8 .. +7 where f = m*36+os.
__global__ __launch_bounds__(256) void k_reduce_squash(
    const float* __restrict__ partU, const float* __restrict__ pb,
    ushort* __restrict__ u_bf)
{
    int t = blockIdx.x * 256 + threadIdx.x;              // 294912 threads
    int b = t / 1152;
    int lb = (t % 1152) * 8;
    int oc0 = lb / 36, s0 = lb - oc0 * 36;               // s0 multiple of 4
    float vals[8] = {0.f, 0.f, 0.f, 0.f, 0.f, 0.f, 0.f, 0.f};
    #pragma unroll
    for (int p = 0; p < 6; p++) {
        const float* base = partU + (size_t)p * 2359296;
        if (s0 <= 28) {
            const float4* pp = (const float4*)(base + (size_t)oc0 * 9216 + b * 36 + s0);
            float4 x = pp[0], y = pp[1];
            vals[0] += x.x; vals[1] += x.y; vals[2] += x.z; vals[3] += x.w;
            vals[4] += y.x; vals[5] += y.y; vals[6] += y.z; vals[7] += y.w;
        } else {                                          // s0 == 32: split 4|4
            const float4* pa = (const float4*)(base + (size_t)oc0 * 9216 + b * 36 + 32);
            const float4* pbq = (const float4*)(base + (size_t)(oc0 + 1) * 9216 + b * 36);
            float4 x = pa[0], y = pbq[0];
            vals[0] += x.x; vals[1] += x.y; vals[2] += x.z; vals[3] += x.w;
            vals[4] += y.x; vals[5] += y.y; vals[6] += y.z; vals[7] += y.w;
        }
    }
    float sn = 0.f;
    #pragma unroll
    for (int e = 0; e < 8; e++) {
        int oc = oc0 + ((s0 + e) >= 36 ? 1 : 0);
        vals[e] += pb[oc];
        sn += vals[e] * vals[e];
    }
    float sc = sqrtf(sn) / (1.f + sn);
    u16x8 o8;
    #pragma unroll
    for (int e = 0; e < 8; e++) o8[e] = f2bf(vals[e] * sc);
    *(u16x8*)(u_bf + (size_t)t * 8) = o8;
}

// ---------------- s_j with inline softmax (Wt [160][9216]; kc split 16) ---------
__global__ __launch_bounds__(320) void k_sj_fused(
    const ushort* __restrict__ u_bf,          // [256][9216] bf16
    const __hip_bfloat16* __restrict__ Wt,    // [160][9216] bf16 (transposed)
    const float* __restrict__ expb,           // [1152][10]
    float* __restrict__ partS,                // [32][256*160]
    int iter)
{
    __shared__ ushort ush[8 * 576];
    __shared__ float cf[720];
    __shared__ float sred[320];
    __shared__ float sinv[10];
    const int tid = threadIdx.x;
    const int bj = blockIdx.x >> 3;                         // 0..63
    const int kc = (blockIdx.x & 7) * 2 + (bj >> 5);        // 0..15
    const int bt = bj & 31;                                 // 0..31
    const int co = tid % 160, half = tid / 160;

    if (iter > 0) {
        int c = tid % 10, g = tid / 10;                  // 10 x 32 partition
        float s = 0.f;
        for (int r = g; r < 1152; r += 32) s += expb[r * 10 + c];
        sred[tid] = s;
        for (int i = tid; i < 720; i += 320) cf[i] = expb[kc * 720 + i];
        __syncthreads();
        if (tid < 10) {
            float t2 = 0.f;
            #pragma unroll
            for (int gg = 0; gg < 32; gg++) t2 += sred[tid + gg * 10];
            sinv[tid] = 1.f / t2;
        }
    }
    for (int i = tid; i < 576; i += 320)      // 8 b x 72 uint4
        ((uint4*)ush)[i] = ((const uint4*)u_bf)[(size_t)(bt * 8 + (i / 72)) * 1152
                                                + kc * 72 + (i % 72)];
    __syncthreads();

    const int cc = co >> 4;
    const float scl = (iter > 0) ? sinv[cc] : 0.f;
    const float cuni = 1.f / 1152.f;
    const ushort* wp = (const ushort*)Wt + (size_t)co * 9216 + kc * 576 + half * 288;

    float acc[8] = {0.f, 0.f, 0.f, 0.f, 0.f, 0.f, 0.f, 0.f};
    for (int rr = 0; rr < 36; rr++) {
        float cl = (iter == 0) ? cuni : cf[(half * 36 + rr) * 10 + cc] * scl;
        u16x8 wq = *(const u16x8*)(wp + rr * 8);
        float wv[8];
        #pragma unroll
        for (int ii = 0; ii < 8; ii++)
            wv[ii] = b2f(wq[ii]) * cl;
        int kbase = half * 288 + rr * 8;
        #pragma unroll
        for (int bb = 0; bb < 8; bb++) {
            u16x8 uq = *(const u16x8*)&ush[bb * 576 + kbase];
            #pragma unroll
            for (int ii = 0; ii < 8; ii++)
                acc[bb] += wv[ii] * b2f(uq[ii]);
        }
    }
    float* ps = partS + (kc * 2 + half) * 40960;
    #pragma unroll
    for (int bb = 0; bb < 8; bb++)
        ps[(bt * 8 + bb) * 160 + co] = acc[bb];
}

// ---------------- v = squash(sum partS); final iter also runs classifiers -------
__global__ __launch_bounds__(320) void k_vj_cls(
    const float* __restrict__ partS, float* __restrict__ v,
    const float* __restrict__ w1, const float* __restrict__ b1,
    const float* __restrict__ w2, const float* __restrict__ b2,
    float* __restrict__ out, int write_out)
{
    const int b = blockIdx.x;
    const int tid = threadIdx.x;
    __shared__ float feat[160];
    if (tid < 160) {
        float s = 0.f;
        #pragma unroll
        for (int p = 0; p < 32; p++) s += partS[p * 40960 + b * 160 + tid];
        float vv = s * fabsf(s) / (1.f + s * s);
        v[b * 160 + tid] = vv;
        feat[tid] = vv;
        if (write_out) out[b * 160 + tid] = vv;
    }
    if (!write_out) return;
    __syncthreads();
    int k = tid >> 5, j = tid & 31;                      // 10 classifiers x 32 lanes
    float acc = 0.f;
    for (int h = j; h < 100; h += 32) {
        float a = b1[k * 100 + h];
        for (int f = 0; f < 160; f++) a += feat[f] * w1[(k * 160 + f) * 100 + h];
        acc += fmaxf(a, 0.f) * w2[k * 100 + h];
    }
    #pragma unroll
    for (int d = 16; d > 0; d >>= 1) acc += __shfl_xor(acc, d);
    if (j == 0)
        out[40960 + b * 10 + k] = 1.f / (1.f + expf(-(acc + b2[k])));
}

// ---------------- M rows for 4 routes + a_ij + bij update + expb ----------------
// Round 21: 288 blocks x 4 routes. One aligned 64B u_bf load per (b, block)
// covers all 4 routes (old: 16B = quarter-line). Per-route arithmetic order
// identical to the 1-route version -> bit-exact. XCD-contiguous route ranges.
__global__ __launch_bounds__(320) void k_mmat_aij(
    const ushort* __restrict__ u_bf, const float* __restrict__ v,
    const float* __restrict__ W, float* __restrict__ bij,
    float* __restrict__ expb)
{
    const int r0 = ((blockIdx.x & 7) * 36 + (blockIdx.x >> 3)) * 4;
    const int tid = threadIdx.x;
    const int co = tid % 160, bh = tid / 160;
    float acc[4][8];
    #pragma unroll
    for (int rt = 0; rt < 4; rt++)
        #pragma unroll
        for (int j = 0; j < 8; j++) acc[rt][j] = 0.f;
    for (int b = bh; b < 256; b += 2) {
        float vv = v[b * 160 + co];
        const u16x8* up = (const u16x8*)(u_bf + (size_t)b * 9216 + r0 * 8);
        #pragma unroll
        for (int rt = 0; rt < 4; rt++) {
            u16x8 uq = up[rt];
            #pragma unroll
            for (int j = 0; j < 8; j++) acc[rt][j] += vv * b2f(uq[j]);
        }
    }
    __shared__ float red[2560];               // [j][bh][co], reused per route
    __shared__ float Ml[4][8][160];
    #pragma unroll
    for (int rt = 0; rt < 4; rt++) {
        __syncthreads();                      // prev route's red reads done
        #pragma unroll
        for (int j = 0; j < 8; j++) red[j * 320 + bh * 160 + co] = acc[rt][j];
        __syncthreads();
        if (tid < 160) {
            #pragma unroll
            for (int j = 0; j < 8; j++)
                Ml[rt][j][tid] = (red[j * 320 + tid] + red[j * 320 + 160 + tid])
                                 * (1.f / 256.f);
        }
    }
    __syncthreads();
    int c = tid >> 5, j32 = tid & 31;                    // 10 c x 32 lanes
    #pragma unroll
    for (int rt = 0; rt < 4; rt++) {
        int r = r0 + rt;
        const float* wr = W + ((size_t)r * 10 + c) * 128;   // W[r][c][o][i] flat
        float a2 = 0.f;
        #pragma unroll
        for (int m = 0; m < 4; m++) {
            int idx = j32 + m * 32;                      // = o*8 + i
            int o = idx >> 3, i = idx & 7;
            a2 += wr[idx] * Ml[rt][i][c * 16 + o];
        }
        #pragma unroll
        for (int d = 16; d > 0; d >>= 1) a2 += __shfl_xor(a2, d);
        if (j32 == 0) {
            float nb = bij[c * 1152 + r] + a2;
            bij[c * 1152 + r] = nb;
            expb[r * 10 + c] = expf(nb);
        }
    }
}

extern "C" void kernel_launch(void* const* d_in, const int* in_sizes, int n_in,
                              void* d_out, int out_size, void* d_ws, size_t ws_size,
                              hipStream_t stream) {
    const float* data    = (const float*)d_in[0];
    const float* conv1_w = (const float*)d_in[1];
    const float* conv1_b = (const float*)d_in[2];
    const float* conv2_w = (const float*)d_in[3];
    const float* conv2_b = (const float*)d_in[4];
    const float* prim_w  = (const float*)d_in[5];
    const float* prim_b  = (const float*)d_in[6];
    const float* W       = (const float*)d_in[7];
    const float* cls_w1  = (const float*)d_in[8];
    const float* cls_b1  = (const float*)d_in[9];
    const float* cls_w2  = (const float*)d_in[10];
    const float* cls_b2  = (const float*)d_in[11];
    float* out = (float*)d_out;

    char* ws = (char*)d_ws;
    // NOTE: conv2 reads P1t while writing P2t -> disjoint. zpage (128B zeros,
    // conv2 padding taps) lives in the unused gap between P2t and P1t.
    float*          partU = (float*)(ws + 0);                   // 56,623,104
    __hip_bfloat16* P2t   = (__hip_bfloat16*)(ws + 56623104);   // 13,107,200
    ushort*         zpage = (ushort*)(ws + 69730304);           //        128
    __hip_bfloat16* P1t   = (__hip_bfloat16*)(ws + 94633984);   // 47,316,992
    __hip_bfloat16* Awt   = (__hip_bfloat16*)(ws + 141950976);  //  5,308,416
    __hip_bfloat16* Wt    = (__hip_bfloat16*)(ws + 147259392);  //  2,949,120
    ushort*         u_bf  = (ushort*)(ws + 150208512);          //  4,718,592
    float*          partS = (float*)(ws + 154927104);           //  5,242,880
    float*          v     = (float*)(ws + 163446784);           //    163,840
    float*          bij   = (float*)(ws + 163610624);           //     46,080
    float*          expb  = (float*)(ws + 163656704);           //     46,080
    __hip_bfloat16* Aw2   = (__hip_bfloat16*)(ws + 163702784);  //    147,456
    __hip_bfloat16* Aw1   = (__hip_bfloat16*)(ws + 163850240);  //      4,096
    // total: 163,854,336 bytes

    hipMemsetAsync(bij, 0, 11520 * sizeof(float), stream);
    hipMemsetAsync(zpage, 0, 128, stream);

    k_prep_fused<<<696, 256, 0, stream>>>(conv1_w, conv2_w, prim_w, W,
                                          Aw1, Aw2, Awt, Wt);
    k_conv1_mfma<<<9728, 256, 0, stream>>>(data, Aw1, conv1_b, P1t);
    k_conv2_pool_mfma<<<3200, 256, 0, stream>>>(P1t, Aw2, conv2_b, zpage, P2t);
    k_primcaps_mfma<<<864, 256, 0, stream>>>(P2t, Awt, partU);
    k_reduce_squash<<<1152, 256, 0, stream>>>(partU, prim_b, u_bf);

    for (int it = 0; it < 3; it++) {
        k_sj_fused<<<512, 320, 0, stream>>>(u_bf, Wt, expb, partS, it);
        k_vj_cls<<<256, 320, 0, stream>>>(partS, v, cls_w1, cls_b1, cls_w2,
                                          cls_b2, out, it == 2 ? 1 : 0);
        if (it < 2)
            k_mmat_aij<<<288, 320, 0, stream>>>(u_bf, v, W, bij, expb);
    }
}

// Round 13
// 537.701 us; speedup vs baseline: 1.0498x; 1.0498x over previous
//
#include <hip/hip_runtime.h>
#include <hip/hip_bf16.h>

// CapsNet forward. Round 24: clean re-submission of the session-best
// configuration (round 9 / 549.8us): single-route XCD-swizzled k_mmat_aij
// (grid 1152), conv2/primcaps at the verified 2-phase structural ceiling
// (~604 TF; swizzle/coalescing/occupancy/spill all counter-verified optimal).
// absmax must be exactly 0.0003356934.
// B=256, R=1152, C=10, O=16, I=8

typedef __bf16 bf16x8 __attribute__((ext_vector_type(8)));
typedef float  f32x4  __attribute__((ext_vector_type(4)));
typedef ushort u16x8  __attribute__((ext_vector_type(8)));

static __device__ __forceinline__ ushort f2bf(float f) {
    __hip_bfloat16 h = __float2bfloat16(f);
    return *(ushort*)&h;
}
static __device__ __forceinline__ float b2f(ushort u) {
    return __uint_as_float(((unsigned)u) << 16);
}

// direct global->LDS DMA, 16B per lane; LDS dest = wave-uniform base + lane*16
typedef __attribute__((address_space(1))) const unsigned int* as1_u32p;
typedef __attribute__((address_space(3))) unsigned int* as3_u32p;
static __device__ __forceinline__ void gl16(const void* g, void* l) {
    __builtin_amdgcn_global_load_lds((as1_u32p)g, (as3_u32p)l, 16, 0, 0);
}

// ---------------- fused prep: Awt (256) | Wt (144) | small (296) ----------------
__global__ __launch_bounds__(256) void k_prep_fused(
    const float* __restrict__ w1, const float* __restrict__ w2,
    const float* __restrict__ pw, const float* __restrict__ W,
    __hip_bfloat16* __restrict__ Aw1, __hip_bfloat16* __restrict__ Aw2,
    __hip_bfloat16* __restrict__ Awt, __hip_bfloat16* __restrict__ Wt)
{
    __shared__ float ls[10368];               // 41.5 KB (max of both transposes)
    const int bid = blockIdx.x;
    const int tid = threadIdx.x;
    if (bid < 256) {
        // Awt[oc][k81][ic] = pw[oc][ic][k81]; stride-81 LDS read: conflict-free
        const int oc = bid;
        const float* src = pw + oc * 10368;
        for (int i = tid; i < 10368; i += 256) ls[i] = src[i];
        __syncthreads();
        __hip_bfloat16* dst = Awt + oc * 10368;
        for (int o = tid; o < 10368; o += 256) {
            int k81 = o >> 7, ic = o & 127;
            dst[o] = __float2bfloat16(ls[ic * 81 + k81]);
        }
    } else if (bid < 400) {
        // Wt[co][r*8+i] = W[r][c][o][i]; 8 rows of 1280 padded to 1281
        const int r0 = (bid - 256) * 8;
        const float* src = W + (size_t)r0 * 1280;
        for (int i = tid; i < 10240; i += 256) {
            int rr = i / 1280, rem = i - rr * 1280;
            ls[rr * 1281 + rem] = src[i];
        }
        __syncthreads();
        for (int o = tid; o < 10240; o += 256) {
            int co = o >> 6, rem = o & 63;
            int rr = rem >> 3, i = rem & 7;
            Wt[(size_t)co * 9216 + r0 * 8 + rem] =
                __float2bfloat16(ls[rr * 1281 + co * 8 + i]);
        }
    } else {
        int t = (bid - 400) * 256 + tid;      // 75,776 threads
        if (t < 73728) {
            int oc = t / 576, rem = t % 576;
            int k9 = rem >> 6, ic = rem & 63;
            Aw2[t] = __float2bfloat16(w2[(oc * 64 + ic) * 9 + k9]);
        } else if (t < 75776) {
            int q = t - 73728;
            int oc = q >> 5, k = q & 31;
            Aw1[q] = __float2bfloat16(k < 27 ? w1[oc * 27 + k] : 0.f);
        }
    }
}

// ---------------- conv1(3->64,3x3,s1,p0) + relu + maxpool(2,2,p1) via MFMA -------
__global__ __launch_bounds__(256) void k_conv1_mfma(
    const float* __restrict__ data, const __hip_bfloat16* __restrict__ Aw1,
    const float* __restrict__ b1, __hip_bfloat16* __restrict__ P1t)
{
    __shared__ float tile[960];          // [ic]*312 + [rloc]*78 + [lc]; lc = x_in+1
    const int tid = threadIdx.x;
    const int py = blockIdx.x % 38, b = blockIdx.x / 38;

    #pragma unroll
    for (int c = 0; c < 4; c++) {
        int idx = tid + c * 256;
        if (idx < 960) {
            float val = 0.f;
            if (idx < 936) {
                int ic = idx / 312, rem = idx % 312;
                int rl = rem / 78, lc = rem % 78;
                int ri = 2 * py - 1 + rl, xi = lc - 1;
                if ((unsigned)ri < 76u && (unsigned)xi < 76u)
                    val = data[(b * 3 + ic) * 5776 + ri * 76 + xi];
            }
            tile[idx] = val;
        }
    }

    const int wave = tid >> 6, lane = tid & 63;
    const int l15 = lane & 15, quad = lane >> 4;

    bf16x8 af = *(const bf16x8*)((const ushort*)Aw1 + (wave * 16 + l15) * 32 + quad * 8);

    int koff[8]; bool kok[8];
    #pragma unroll
    for (int j = 0; j < 8; j++) {
        int kk = quad * 8 + j;
        kok[j] = kk < 27;
        int ic = kk / 9, rem = kk - ic * 9, ky = rem / 3, kx = rem - ky * 3;
        koff[j] = kok[j] ? (ic * 312 + ky * 78 + kx) : 0;
    }

    float bias[4];
    #pragma unroll
    for (int r = 0; r < 4; r++) bias[r] = b1[wave * 16 + quad * 4 + r];

    const bool valid0 = (py > 0);
    const bool valid1 = (py < 37);

    __syncthreads();

    #pragma unroll
    for (int t5 = 0; t5 < 5; t5++) {
        int n_x = t5 * 16 + l15;                         // conv x = n_x - 1
        bool col_ok = (unsigned)(n_x - 1) < 74u;

        bf16x8 bf0, bf1;
        #pragma unroll
        for (int j = 0; j < 8; j++) {
            float v0 = tile[koff[j] + n_x];
            float v1 = tile[koff[j] + 78 + n_x];
            bool ok = col_ok && kok[j];
            bf0[j] = (__bf16)(ok ? v0 : 0.f);
            bf1[j] = (__bf16)(ok ? v1 : 0.f);
        }
        f32x4 z = {0.f, 0.f, 0.f, 0.f};
        f32x4 c0 = __builtin_amdgcn_mfma_f32_16x16x32_bf16(af, bf0, z, 0, 0, 0);
        f32x4 c1 = __builtin_amdgcn_mfma_f32_16x16x32_bf16(af, bf1, z, 0, 0, 0);

        f32x4 p;
        #pragma unroll
        for (int r = 0; r < 4; r++) {
            float r0 = (valid0 && col_ok) ? fmaxf(c0[r] + bias[r], 0.f) : 0.f;
            float r1 = (valid1 && col_ok) ? fmaxf(c1[r] + bias[r], 0.f) : 0.f;
            p[r] = fmaxf(r0, r1);
        }
        #pragma unroll
        for (int r = 0; r < 4; r++)
            p[r] = fmaxf(p[r], __shfl_xor(p[r], 1));

        if (!(l15 & 1)) {
            int px = t5 * 8 + (l15 >> 1);
            if (px < 38) {
                ushort4 pk;
                pk.x = f2bf(p[0]); pk.y = f2bf(p[1]);
                pk.z = f2bf(p[2]); pk.w = f2bf(p[3]);
                *(ushort4*)((ushort*)P1t + ((size_t)(b * 38 + py) * 38 + px) * 64
                            + wave * 16 + quad * 4) = pk;
            }
        }
    }
}

// ---------------- conv2 MFMA + bias + relu + FUSED maxpool(2,2,p1) --------------
// (256,4): known-good VGPR=64 operating point; stride-136 epilogue gather.
__global__ __launch_bounds__(256, 4) void k_conv2_pool_mfma(
    const __hip_bfloat16* __restrict__ P1t,   // [256][38][38][64]
    const __hip_bfloat16* __restrict__ Aw2,   // [128][576]
    const float* __restrict__ cb,             // [128]
    const ushort* __restrict__ zpage,         // 128 B of zeros
    __hip_bfloat16* __restrict__ P2t)         // [256][20][20][128]
{
    __shared__ ushort lA[128 * 64];           // 16,384 B linear
    __shared__ ushort lB[128 * 64];           // 16,384 B linear
    const int tid  = threadIdx.x;
    const int grp  = blockIdx.x / 50, toff = blockIdx.x % 50;
    const int wave = tid >> 6, lane = tid & 63;
    const int wm   = wave & 1, wn = wave >> 1;      // 2 x 2 waves
    const int lane15 = lane & 15, quad = lane >> 4;

    const int sl = ((lane & 7) ^ (lane >> 3)) * 8;   // pre-swizzled source slot

    int oA[4], oB[4], yv[4], xv[4];
    #pragma unroll
    for (int i = 0; i < 4; i++) {
        int row = wave * 32 + i * 8 + (lane >> 3);
        oA[i] = row * 576 + sl;
        int off = toff * 128 + row;                  // 0..6399 within group
        int bb = off / 1600, rem = off % 1600;
        int cell = rem >> 2, q = rem & 3;
        int py = cell / 20, px = cell % 20;
        int y = 2 * py - 1 + (q >> 1), x = 2 * px - 1 + (q & 1);
        yv[i] = y; xv[i] = x;
        oB[i] = (((grp * 4 + bb) * 38 + (y - 1)) * 38 + (x - 1)) * 64 + sl;
    }
    ushort* lAq = &lA[wave * 2048];
    ushort* lBq = &lB[wave * 2048];

    const int s7 = lane15 & 7;
    const int c0 = (quad ^ s7) * 8;                  // kk=0 slot (ushorts)
    const int c1 = ((quad + 4) ^ s7) * 8;            // kk=1 slot
    const ushort* aRd0 = &lA[(wm * 64 + lane15) * 64 + c0];
    const ushort* aRd1 = &lA[(wm * 64 + lane15) * 64 + c1];
    const ushort* bRd0 = &lB[(wn * 64 + lane15) * 64 + c0];
    const ushort* bRd1 = &lB[(wn * 64 + lane15) * 64 + c1];

    f32x4 zero = {0.f, 0.f, 0.f, 0.f};
    f32x4 acc[4][4];
    #pragma unroll
    for (int i = 0; i < 4; i++)
        #pragma unroll
        for (int j = 0; j < 4; j++) acc[i][j] = zero;

    for (int kb = 0; kb < 9; kb++) {                      // tap (ky,kx), 64 ic each
        int ky = kb / 3, kx = kb - ky * 3;
        int dB = (ky * 38 + kx) << 6;
        int dA = kb << 6;

        __syncthreads();                                  // prev reads done
        #pragma unroll
        for (int i = 0; i < 4; i++) {
            gl16((const ushort*)Aw2 + oA[i] + dA, lAq + i * 512);
            bool ok = ((unsigned)(yv[i] - 1 + ky) < 38u) &&
                      ((unsigned)(xv[i] - 1 + kx) < 38u);
            const ushort* src = ok ? ((const ushort*)P1t + (ptrdiff_t)(oB[i] + dB))
                                   : (zpage + sl);
            gl16(src, lBq + i * 512);
        }
        __syncthreads();                                  // DMA drained

        #pragma unroll
        for (int kk = 0; kk < 2; kk++) {
            const ushort* ap = kk ? aRd1 : aRd0;
            const ushort* bp = kk ? bRd1 : bRd0;
            bf16x8 af[4], bf[4];
            #pragma unroll
            for (int tm = 0; tm < 4; tm++)
                af[tm] = *(const bf16x8*)(ap + tm * 1024);
            #pragma unroll
            for (int tn = 0; tn < 4; tn++)
                bf[tn] = *(const bf16x8*)(bp + tn * 1024);
            #pragma unroll
            for (int tm = 0; tm < 4; tm++)
                #pragma unroll
                for (int tn = 0; tn < 4; tn++)
                    acc[tm][tn] = __builtin_amdgcn_mfma_f32_16x16x32_bf16(
                        af[tm], bf[tn], acc[tm][tn], 0, 0, 0);
        }
    }

    // epilogue: relu(val+bias), zero invalid quadrants, pool via shfl,
    // gather eq==0 results in LDS [32 cells][136 stride], coalesced burst out.
    __syncthreads();                          // all MFMA-phase LDS reads done
    ushort* lout = lA;                        // reuse (32*136 ushorts = 8.5KB)
    #pragma unroll
    for (int tn = 0; tn < 4; tn++) {
        int woff = toff * 128 + wn * 64 + tn * 16 + lane15;
        int ebb = woff / 1600, erem = woff % 1600;
        int ecell = erem >> 2, eq = erem & 3;
        int epy = ecell / 20, epx = ecell % 20;
        int ey = 2 * epy - 1 + (eq >> 1), ex = 2 * epx - 1 + (eq & 1);
        bool vq = ((unsigned)ey < 38u) && ((unsigned)ex < 38u);
        int c32 = wn * 16 + tn * 4 + (lane15 >> 2);      // block-local cell
        #pragma unroll
        for (int tm = 0; tm < 4; tm++) {
            int m0 = wm * 64 + tm * 16 + quad * 4;
            f32x4 a = acc[tm][tn];
            f32x4 p;
            #pragma unroll
            for (int r = 0; r < 4; r++)
                p[r] = vq ? fmaxf(a[r] + cb[m0 + r], 0.f) : 0.f;
            #pragma unroll
            for (int r = 0; r < 4; r++) {
                p[r] = fmaxf(p[r], __shfl_xor(p[r], 1));
                p[r] = fmaxf(p[r], __shfl_xor(p[r], 2));
            }
            if (eq == 0) {
                ushort4 pk;
                pk.x = f2bf(p[0]); pk.y = f2bf(p[1]);
                pk.z = f2bf(p[2]); pk.w = f2bf(p[3]);
                *(ushort4*)(lout + c32 * 136 + m0) = pk;
            }
        }
    }
    __syncthreads();
    {
        int c32 = tid >> 3, part = tid & 7;              // 8 threads x 32B per cell
        int woff = toff * 128 + c32 * 4;                 // the q==0 row of the cell
        int ebb = woff / 1600, erem = woff % 1600;
        int ecell = erem >> 2;
        int epy = ecell / 20, epx = ecell % 20;
        int eb = grp * 4 + ebb;
        const uint4* src = (const uint4*)(lout + c32 * 136 + part * 16);
        uint4* dst = (uint4*)((ushort*)P2t
                     + (((size_t)eb * 20 + epy) * 20 + epx) * 128 + part * 16);
        dst[0] = src[0];
        dst[1] = src[1];
    }
}

// ---------------- primcaps split-K MFMA GEMM, 128x128 tile, gl16 staging --------
__global__ __launch_bounds__(256, 4) void k_primcaps_mfma(
    const __hip_bfloat16* __restrict__ P2t,   // [256][20][20][128]
    const __hip_bfloat16* __restrict__ Awt,   // [256][10368]
    float* __restrict__ partU)                // [6][256][9216]
{
    __shared__ ushort lA[128 * 64];           // 16,384 B linear
    __shared__ ushort lB[128 * 64];           // 16,384 B linear
    const int tid  = threadIdx.x;
    const int chunk = blockIdx.x / 144;
    const int tile  = blockIdx.x % 144;
    const int bm   = tile & 1;
    const int bn   = tile >> 1;               // 0..71
    const int wave = tid >> 6, lane = tid & 63;
    const int wm   = wave & 1, wn = wave >> 1;
    const int lane15 = lane & 15, quad = lane >> 4;

    const int sl = ((lane & 7) ^ (lane >> 3)) * 8;

    int oA[4], oB[4];
    #pragma unroll
    for (int i = 0; i < 4; i++) {
        int row = wave * 32 + i * 8 + (lane >> 3);
        oA[i] = (bm * 128 + row) * 10368 + sl;
        int n = bn * 128 + row;
        int cbn = n / 36, cs = n % 36;
        int cy = cs / 6, cx = cs % 6;
        oB[i] = ((cbn * 20 + 2 * cy) * 20 + 2 * cx) * 128 + sl;
    }
    ushort* lAq = &lA[wave * 2048];
    ushort* lBq = &lB[wave * 2048];

    const int s7 = lane15 & 7;
    const int c0 = (quad ^ s7) * 8;
    const int c1 = ((quad + 4) ^ s7) * 8;
    const ushort* aRd0 = &lA[(wm * 64 + lane15) * 64 + c0];
    const ushort* aRd1 = &lA[(wm * 64 + lane15) * 64 + c1];
    const ushort* bRd0 = &lB[(wn * 64 + lane15) * 64 + c0];
    const ushort* bRd1 = &lB[(wn * 64 + lane15) * 64 + c1];

    f32x4 zero = {0.f, 0.f, 0.f, 0.f};
    f32x4 acc[4][4];
    #pragma unroll
    for (int i = 0; i < 4; i++)
        #pragma unroll
        for (int j = 0; j < 4; j++) acc[i][j] = zero;

    const int kb0 = chunk * 27;
    for (int ki = 0; ki < 27; ki++) {
        int kb = kb0 + ki;
        int k81 = kb >> 1;
        int ky = k81 / 9, kx = k81 - ky * 9;
        int dB = (ky * 20 + kx) * 128 + (kb & 1) * 64;
        int dA = kb << 6;

        __syncthreads();
        #pragma unroll
        for (int i = 0; i < 4; i++) {
            gl16((const ushort*)Awt + (size_t)oA[i] + dA, lAq + i * 512);
            gl16((const ushort*)P2t + oB[i] + dB, lBq + i * 512);
        }
        __syncthreads();

        #pragma unroll
        for (int kk = 0; kk < 2; kk++) {
            const ushort* ap = kk ? aRd1 : aRd0;
            const ushort* bp = kk ? bRd1 : bRd0;
            bf16x8 af[4], bf[4];
            #pragma unroll
            for (int tm = 0; tm < 4; tm++)
                af[tm] = *(const bf16x8*)(ap + tm * 1024);
            #pragma unroll
            for (int tn = 0; tn < 4; tn++)
                bf[tn] = *(const bf16x8*)(bp + tn * 1024);
            #pragma unroll
            for (int tm = 0; tm < 4; tm++)
                #pragma unroll
                for (int tn = 0; tn < 4; tn++)
                    acc[tm][tn] = __builtin_amdgcn_mfma_f32_16x16x32_bf16(
                        af[tm], bf[tn], acc[tm][tn], 0, 0, 0);
        }
    }

    float* base = partU + (size_t)chunk * 2359296;
    #pragma unroll
    for (int tm = 0; tm < 4; tm++) {
        int m0 = bm * 128 + wm * 64 + tm * 16 + quad * 4;
        #pragma unroll
        for (int tn = 0; tn < 4; tn++) {
            int nn = bn * 128 + wn * 64 + tn * 16 + lane15;
            f32x4 a = acc[tm][tn];
            #pragma unroll
            for (int r = 0; r < 4; r++)
                base[(size_t)(m0 + r) * 9216 + nn] = a[r];   // lane-consecutive
        }
    }
}

// ---------------- reduce 6 partials + bias + squash -> u_bf [b][k] bf16 ----------
// partU layout [chunk][m(256)][n=b*36+os]; thread t covers b=t/1152,
// flat f = (t%1152)*8 .. +7 where f = m*36+os.
__global__ __launch_bounds__(256) void k_reduce_squash(
    const float* __restrict__ partU, const float* __restrict__ pb,
    ushort* __restrict__ u_bf)
{
    int t = blockIdx.x * 256 + threadIdx.x;              // 294912 threads
    int b = t / 1152;
    int lb = (t % 1152) * 8;
    int oc0 = lb / 36, s0 = lb - oc0 * 36;               // s0 multiple of 4
    float vals[8] = {0.f, 0.f, 0.f, 0.f, 0.f, 0.f, 0.f, 0.f};
    #pragma unroll
    for (int p = 0; p < 6; p++) {
        const float* base = partU + (size_t)p * 2359296;
        if (s0 <= 28) {
            const float4* pp = (const float4*)(base + (size_t)oc0 * 9216 + b * 36 + s0);
            float4 x = pp[0], y = pp[1];
            vals[0] += x.x; vals[1] += x.y; vals[2] += x.z; vals[3] += x.w;
            vals[4] += y.x; vals[5] += y.y; vals[6] += y.z; vals[7] += y.w;
        } else {                                          // s0 == 32: split 4|4
            const float4* pa = (const float4*)(base + (size_t)oc0 * 9216 + b * 36 + 32);
            const float4* pbq = (const float4*)(base + (size_t)(oc0 + 1) * 9216 + b * 36);
            float4 x = pa[0], y = pbq[0];
            vals[0] += x.x; vals[1] += x.y; vals[2] += x.z; vals[3] += x.w;
            vals[4] += y.x; vals[5] += y.y; vals[6] += y.z; vals[7] += y.w;
        }
    }
    float sn = 0.f;
    #pragma unroll
    for (int e = 0; e < 8; e++) {
        int oc = oc0 + ((s0 + e) >= 36 ? 1 : 0);
        vals[e] += pb[oc];
        sn += vals[e] * vals[e];
    }
    float sc = sqrtf(sn) / (1.f + sn);
    u16x8 o8;
    #pragma unroll
    for (int e = 0; e < 8; e++) o8[e] = f2bf(vals[e] * sc);
    *(u16x8*)(u_bf + (size_t)t * 8) = o8;
}

// ---------------- s_j with inline softmax (Wt [160][9216]; kc split 16) ---------
__global__ __launch_bounds__(320) void k_sj_fused(
    const ushort* __restrict__ u_bf,          // [256][9216] bf16
    const __hip_bfloat16* __restrict__ Wt,    // [160][9216] bf16 (transposed)
    const float* __restrict__ expb,           // [1152][10]
    float* __restrict__ partS,                // [32][256*160]
    int iter)
{
    __shared__ ushort ush[8 * 576];
    __shared__ float cf[720];
    __shared__ float sred[320];
    __shared__ float sinv[10];
    const int tid = threadIdx.x;
    const int bj = blockIdx.x >> 3;                         // 0..63
    const int kc = (blockIdx.x & 7) * 2 + (bj >> 5);        // 0..15
    const int bt = bj & 31;                                 // 0..31
    const int co = tid % 160, half = tid / 160;

    if (iter > 0) {
        int c = tid % 10, g = tid / 10;                  // 10 x 32 partition
        float s = 0.f;
        for (int r = g; r < 1152; r += 32) s += expb[r * 10 + c];
        sred[tid] = s;
        for (int i = tid; i < 720; i += 320) cf[i] = expb[kc * 720 + i];
        __syncthreads();
        if (tid < 10) {
            float t2 = 0.f;
            #pragma unroll
            for (int gg = 0; gg < 32; gg++) t2 += sred[tid + gg * 10];
            sinv[tid] = 1.f / t2;
        }
    }
    for (int i = tid; i < 576; i += 320)      // 8 b x 72 uint4
        ((uint4*)ush)[i] = ((const uint4*)u_bf)[(size_t)(bt * 8 + (i / 72)) * 1152
                                                + kc * 72 + (i % 72)];
    __syncthreads();

    const int cc = co >> 4;
    const float scl = (iter > 0) ? sinv[cc] : 0.f;
    const float cuni = 1.f / 1152.f;
    const ushort* wp = (const ushort*)Wt + (size_t)co * 9216 + kc * 576 + half * 288;

    float acc[8] = {0.f, 0.f, 0.f, 0.f, 0.f, 0.f, 0.f, 0.f};
    for (int rr = 0; rr < 36; rr++) {
        float cl = (iter == 0) ? cuni : cf[(half * 36 + rr) * 10 + cc] * scl;
        u16x8 wq = *(const u16x8*)(wp + rr * 8);
        float wv[8];
        #pragma unroll
        for (int ii = 0; ii < 8; ii++)
            wv[ii] = b2f(wq[ii]) * cl;
        int kbase = half * 288 + rr * 8;
        #pragma unroll
        for (int bb = 0; bb < 8; bb++) {
            u16x8 uq = *(const u16x8*)&ush[bb * 576 + kbase];
            #pragma unroll
            for (int ii = 0; ii < 8; ii++)
                acc[bb] += wv[ii] * b2f(uq[ii]);
        }
    }
    float* ps = partS + (kc * 2 + half) * 40960;
    #pragma unroll
    for (int bb = 0; bb < 8; bb++)
        ps[(bt * 8 + bb) * 160 + co] = acc[bb];
}

// ---------------- v = squash(sum partS); final iter also runs classifiers -------
__global__ __launch_bounds__(320) void k_vj_cls(
    const float* __restrict__ partS, float* __restrict__ v,
    const float* __restrict__ w1, const float* __restrict__ b1,
    const float* __restrict__ w2, const float* __restrict__ b2,
    float* __restrict__ out, int write_out)
{
    const int b = blockIdx.x;
    const int tid = threadIdx.x;
    __shared__ float feat[160];
    if (tid < 160) {
        float s = 0.f;
        #pragma unroll
        for (int p = 0; p < 32; p++) s += partS[p * 40960 + b * 160 + tid];
        float vv = s * fabsf(s) / (1.f + s * s);
        v[b * 160 + tid] = vv;
        feat[tid] = vv;
        if (write_out) out[b * 160 + tid] = vv;
    }
    if (!write_out) return;
    __syncthreads();
    int k = tid >> 5, j = tid & 31;                      // 10 classifiers x 32 lanes
    float acc = 0.f;
    for (int h = j; h < 100; h += 32) {
        float a = b1[k * 100 + h];
        for (int f = 0; f < 160; f++) a += feat[f] * w1[(k * 160 + f) * 100 + h];
        acc += fmaxf(a, 0.f) * w2[k * 100 + h];
    }
    #pragma unroll
    for (int d = 16; d > 0; d >>= 1) acc += __shfl_xor(acc, d);
    if (j == 0)
        out[40960 + b * 10 + k] = 1.f / (1.f + expf(-(acc + b2[k])));
}

// ---------------- M rows for route r + a_ij + bij update + expb -----------------
// XCD swizzle r = (bid&7)*144 + (bid>>3): each XCD owns a contiguous
// 144-route range (round-9 verified-best configuration).
__global__ __launch_bounds__(320) void k_mmat_aij(
    const ushort* __restrict__ u_bf, const float* __restrict__ v,
    const float* __restrict__ W, float* __restrict__ bij,
    float* __restrict__ expb)
{
    const int r = (blockIdx.x & 7) * 144 + (blockIdx.x >> 3);
    const int tid = threadIdx.x;
    const int co = tid % 160, bh = tid / 160;
    float acc[8] = {0.f, 0.f, 0.f, 0.f, 0.f, 0.f, 0.f, 0.f};
    for (int b = bh; b < 256; b += 2) {
        float vv = v[b * 160 + co];
        u16x8 uq = *(const u16x8*)(u_bf + (size_t)b * 9216 + r * 8);
        #pragma unroll
        for (int j = 0; j < 8; j++) acc[j] += vv * b2f(uq[j]);
    }
    __shared__ float red[2560];               // [j][bh][co]
    __shared__ float Ml[8][160];
    #pragma unroll
    for (int j = 0; j < 8; j++) red[j * 320 + bh * 160 + co] = acc[j];
    __syncthreads();
    if (tid < 160) {
        #pragma unroll
        for (int j = 0; j < 8; j++)
            Ml[j][tid] = (red[j * 320 + tid] + red[j * 320 + 160 + tid]) * (1.f / 256.f);
    }
    __syncthreads();
    int c = tid >> 5, j32 = tid & 31;                    // 10 c x 32 lanes
    const float* wr = W + ((size_t)r * 10 + c) * 128;    // W[r][c][o][i] flat
    float a2 = 0.f;
    #pragma unroll
    for (int m = 0; m < 4; m++) {
        int idx = j32 + m * 32;                          // = o*8 + i
        int o = idx >> 3, i = idx & 7;
        a2 += wr[idx] * Ml[i][c * 16 + o];
    }
    #pragma unroll
    for (int d = 16; d > 0; d >>= 1) a2 += __shfl_xor(a2, d);
    if (j32 == 0) {
        float nb = bij[c * 1152 + r] + a2;
        bij[c * 1152 + r] = nb;
        expb[r * 10 + c] = expf(nb);
    }
}

extern "C" void kernel_launch(void* const* d_in, const int* in_sizes, int n_in,
                              void* d_out, int out_size, void* d_ws, size_t ws_size,
                              hipStream_t stream) {
    const float* data    = (const float*)d_in[0];
    const float* conv1_w = (const float*)d_in[1];
    const float* conv1_b = (const float*)d_in[2];
    const float* conv2_w = (const float*)d_in[3];
    const float* conv2_b = (const float*)d_in[4];
    const float* prim_w  = (const float*)d_in[5];
    const float* prim_b  = (const float*)d_in[6];
    const float* W       = (const float*)d_in[7];
    const float* cls_w1  = (const float*)d_in[8];
    const float* cls_b1  = (const float*)d_in[9];
    const float* cls_w2  = (const float*)d_in[10];
    const float* cls_b2  = (const float*)d_in[11];
    float* out = (float*)d_out;

    char* ws = (char*)d_ws;
    // NOTE: conv2 reads P1t while writing P2t -> disjoint. zpage (128B zeros,
    // conv2 padding taps) lives in the unused gap between P2t and P1t.
    float*          partU = (float*)(ws + 0);                   // 56,623,104
    __hip_bfloat16* P2t   = (__hip_bfloat16*)(ws + 56623104);   // 13,107,200
    ushort*         zpage = (ushort*)(ws + 69730304);           //        128
    __hip_bfloat16* P1t   = (__hip_bfloat16*)(ws + 94633984);   // 47,316,992
    __hip_bfloat16* Awt   = (__hip_bfloat16*)(ws + 141950976);  //  5,308,416
    __hip_bfloat16* Wt    = (__hip_bfloat16*)(ws + 147259392);  //  2,949,120
    ushort*         u_bf  = (ushort*)(ws + 150208512);          //  4,718,592
    float*          partS = (float*)(ws + 154927104);           //  5,242,880
    float*          v     = (float*)(ws + 163446784);           //    163,840
    float*          bij   = (float*)(ws + 163610624);           //     46,080
    float*          expb  = (float*)(ws + 163656704);           //     46,080
    __hip_bfloat16* Aw2   = (__hip_bfloat16*)(ws + 163702784);  //    147,456
    __hip_bfloat16* Aw1   = (__hip_bfloat16*)(ws + 163850240);  //      4,096
    // total: 163,854,336 bytes

    hipMemsetAsync(bij, 0, 11520 * sizeof(float), stream);
    hipMemsetAsync(zpage, 0, 128, stream);

    k_prep_fused<<<696, 256, 0, stream>>>(conv1_w, conv2_w, prim_w, W,
                                          Aw1, Aw2, Awt, Wt);
    k_conv1_mfma<<<9728, 256, 0, stream>>>(data, Aw1, conv1_b, P1t);
    k_conv2_pool_mfma<<<3200, 256, 0, stream>>>(P1t, Aw2, conv2_b, zpage, P2t);
    k_primcaps_mfma<<<864, 256, 0, stream>>>(P2t, Awt, partU);
    k_reduce_squash<<<1152, 256, 0, stream>>>(partU, prim_b, u_bf);

    for (int it = 0; it < 3; it++) {
        k_sj_fused<<<512, 320, 0, stream>>>(u_bf, Wt, expb, partS, it);
        k_vj_cls<<<256, 320, 0, stream>>>(partS, v, cls_w1, cls_b1, cls_w2,
                                          cls_b2, out, it == 2 ? 1 : 0);
        if (it < 2)
            k_mmat_aij<<<1152, 320, 0, stream>>>(u_bf, v, W, bij, expb);
    }
}